// Round 6
// baseline (1363.135 us; speedup 1.0000x reference)
//
#include <hip/hip_runtime.h>
#include <math.h>

#define N_NODES 100000
#define N_EDGES 1200000
#define N_GRAPHS 256
#define CH 64
#define NC (N_NODES * CH)
#define EPS 1e-5f

#define ZSTR 136   // f16 units per Z row (128 + pad)
#define NTILES (N_EDGES / 64)

typedef _Float16 half8 __attribute__((ext_vector_type(8)));
typedef float floatx4 __attribute__((ext_vector_type(4)));

// ---------------- embed + BN0 stats fused ----------------
__global__ void embed_stats_kernel(const float* __restrict__ x,
                                   const float* __restrict__ W,   // [12,64]
                                   const float* __restrict__ b,   // [64]
                                   float* __restrict__ out,       // [N,64]
                                   float* __restrict__ stats) {   // [128] pre-zeroed
    int c = threadIdx.x & 63;
    int sub = threadIdx.x >> 6;
    float s = 0.f, q = 0.f;
    for (int r = blockIdx.x * 4 + sub; r < N_NODES; r += gridDim.x * 4) {
        const float* xr = x + r * 12;
        float acc = b[c];
#pragma unroll
        for (int k = 0; k < 12; ++k)
            acc = fmaf(xr[k], W[k * CH + c], acc);
        out[(size_t)r * CH + c] = acc;
        s += acc;
        q = fmaf(acc, acc, q);
    }
    __shared__ float ls[4][64];
    __shared__ float lq[4][64];
    ls[sub][c] = s;
    lq[sub][c] = q;
    __syncthreads();
    if (sub == 0) {
        s = ls[0][c] + ls[1][c] + ls[2][c] + ls[3][c];
        q = lq[0][c] + lq[1][c] + lq[2][c] + lq[3][c];
        atomicAdd(&stats[c], s);
        atomicAdd(&stats[64 + c], q);
    }
}

// ---------------- BN stats (post-aggregation layers) ----------------
__global__ void bn_stats_kernel(const float* __restrict__ a,
                                float* __restrict__ stats) { // [128] pre-zeroed
    int c = threadIdx.x & 63;
    int sub = threadIdx.x >> 6;
    float s = 0.f, q = 0.f;
    for (int r = blockIdx.x * 4 + sub; r < N_NODES; r += gridDim.x * 4) {
        float v = a[(size_t)r * CH + c];
        s += v;
        q = fmaf(v, v, q);
    }
    __shared__ float ls[4][64];
    __shared__ float lq[4][64];
    ls[sub][c] = s;
    lq[sub][c] = q;
    __syncthreads();
    if (sub == 0) {
        s = ls[0][c] + ls[1][c] + ls[2][c] + ls[3][c];
        q = lq[0][c] + lq[1][c] + lq[2][c] + lq[3][c];
        atomicAdd(&stats[c], s);
        atomicAdd(&stats[64 + c], q);
    }
}

// ------- BN apply with fused finalize (+residual, +relu, +f16 copy) -------
template <bool RELU, bool RES, bool F16OUT>
__global__ void bn_apply_kernel(float* __restrict__ a,
                                const float* __restrict__ res,
                                const float* __restrict__ stats,
                                const float* __restrict__ gamma,
                                const float* __restrict__ beta,
                                _Float16* __restrict__ h16) {
    __shared__ float ab[128];
    if (threadIdx.x < 64) {
        int cc = threadIdx.x;
        float mean = stats[cc] * (1.0f / (float)N_NODES);
        float var  = stats[64 + cc] * (1.0f / (float)N_NODES) - mean * mean;
        float inv  = rsqrtf(var + EPS);
        float A = gamma[cc] * inv;
        ab[cc] = A;
        ab[64 + cc] = beta[cc] - mean * A;
    }
    __syncthreads();
    int idx = blockIdx.x * blockDim.x + threadIdx.x;
    if (idx >= NC) return;
    int c = idx & 63;
    float v = fmaf(a[idx], ab[c], ab[64 + c]);
    if (RES) v += res[idx];
    if (RELU) v = fmaxf(v, 0.f);
    a[idx] = v;
    if (F16OUT) h16[idx] = (_Float16)v;
}

// ---------------- counting sort of edges by dst (perm only) ----------------
__global__ void hist_kernel(const int* __restrict__ ei,
                            int* __restrict__ rowptr) { // [N+1] pre-zeroed
    int e = blockIdx.x * blockDim.x + threadIdx.x;
    if (e < N_EDGES) atomicAdd(&rowptr[ei[N_EDGES + e] + 1], 1);
}

__global__ void scan_kernel(int* __restrict__ a, int* __restrict__ cursor) {
    __shared__ int wsum[16];
    __shared__ int carryS;
    int t = threadIdx.x;           // 1024 threads = 16 waves
    int lane = t & 63, w = t >> 6;
    if (t == 0) carryS = 0;
    __syncthreads();
    for (int base = 0; base <= N_NODES; base += 1024) {
        int i = base + t;
        int v = (i <= N_NODES) ? a[i] : 0;
        int s = v;
#pragma unroll
        for (int d = 1; d < 64; d <<= 1) {
            int o = __shfl_up(s, d);
            if (lane >= d) s += o;
        }
        if (lane == 63) wsum[w] = s;
        __syncthreads();
        if (w == 0) {
            int ws2 = (lane < 16) ? wsum[lane] : 0;
#pragma unroll
            for (int d = 1; d < 16; d <<= 1) {
                int o = __shfl_up(ws2, d);
                if (lane >= d) ws2 += o;
            }
            if (lane < 16) wsum[lane] = ws2;
        }
        __syncthreads();
        int waveoff = (w > 0) ? wsum[w - 1] : 0;
        int total = wsum[15];
        int res = s + waveoff + carryS;
        if (i <= N_NODES) {
            a[i] = res;
            if (i < N_NODES) cursor[i] = res;
        }
        __syncthreads();
        if (t == 0) carryS += total;
        __syncthreads();
    }
}

__global__ void scatter_perm_kernel(const int* __restrict__ ei,
                                    int* __restrict__ cursor,
                                    int* __restrict__ perm) {
    int e = blockIdx.x * blockDim.x + threadIdx.x;
    if (e >= N_EDGES) return;
    int d = ei[N_EDGES + e];
    int pos = atomicAdd(&cursor[d], 1);
    perm[pos] = e;
}

// sdst[pos] = d for pos in [rowptr[d], rowptr[d+1])  (coalesced-ish writes)
__global__ void fill_sdst_kernel(const int* __restrict__ rowptr,
                                 int* __restrict__ sdst) {
    int d = blockIdx.x * blockDim.x + threadIdx.x;
    if (d >= N_NODES) return;
    int s = rowptr[d], e = rowptr[d + 1];
    for (int pos = s; pos < e; ++pos) sdst[pos] = d;
}

// ---------------- weight prep: WT[n][k] = W[k][n] in f16 ----------------
__global__ void prep_weights_kernel(const float* __restrict__ Wf,  // [129,64]
                                    const float* __restrict__ Ws,  // [129,64]
                                    const float* __restrict__ bf,
                                    const float* __restrict__ bs,
                                    _Float16* __restrict__ WT,     // [128,128]
                                    float* __restrict__ w128,      // [128]
                                    float* __restrict__ bias) {    // [128]
    int idx = blockIdx.x * blockDim.x + threadIdx.x;  // 16384
    if (idx < 128 * 128) {
        int n = idx >> 7;
        int k = idx & 127;
        float v = (n < 64) ? Wf[k * 64 + n] : Ws[k * 64 + (n - 64)];
        WT[idx] = (_Float16)v;
    }
    if (idx < 128) {
        w128[idx] = (idx < 64) ? Wf[128 * 64 + idx] : Ws[128 * 64 + (idx - 64)];
        bias[idx] = (idx < 64) ? bf[idx] : bs[idx - 64];
    }
}

// ---------------- CGConv edge kernel: f16 MFMA, direct merged atomics -------
// 256 threads = 4 waves; wave w owns output cols [w*16,+16) for f AND s.
// LDS: only the Z tile + dst/ea metadata (~18 KB) => ~7 blocks/CU.
// Epilogue: each lane walks its 16 rows in ascending order, merges runs of
// equal dst in-register, atomicAdds merged sums straight to global agg.
__global__ __launch_bounds__(256, 6)
void edge_mfma_kernel(const _Float16* __restrict__ h16, // [N,64] f16
                      const int* __restrict__ sdst,     // [E] sorted dst
                      const int* __restrict__ perm,     // [E] sorted->orig
                      const int* __restrict__ ei,       // [2,E] original
                      const float* __restrict__ ea,     // [E] original
                      const _Float16* __restrict__ WT,  // [128,128]
                      const float* __restrict__ w128,   // [128]
                      const float* __restrict__ bias,   // [128]
                      float* __restrict__ agg) {        // [N,64] pre-zeroed
    __shared__ __align__(16) _Float16 Zs[64 * ZSTR];
    __shared__ __align__(16) int dstL[64];
    __shared__ __align__(16) float eaL[64];

    const int t = threadIdx.x;
    const int lane = t & 63;
    const int w = t >> 6;          // wave 0..3
    const int l15 = lane & 15;
    const int quad = lane >> 4;    // 0..3
    const int col = w * 16 + l15;  // this lane's output column (f and s)

    half8 wfr[4], wsr[4];
#pragma unroll
    for (int ks = 0; ks < 4; ++ks) {
        wfr[ks] = *(const half8*)(WT + col * 128 + ks * 32 + quad * 8);
        wsr[ks] = *(const half8*)(WT + (64 + col) * 128 + ks * 32 + quad * 8);
    }
    const float biasf = bias[col];
    const float biass = bias[64 + col];
    const float wf128v = w128[col];
    const float ws128v = w128[64 + col];

    for (int tile = blockIdx.x; tile < NTILES; tile += gridDim.x) {
        const int base = tile * 64;

        // ---- stage Z (f16 gather through perm) ----
        {
            const int e = t >> 2, q = t & 3;
            const int p = perm[base + e];
            const int dst = sdst[base + e];
            const int src = ei[p];
            const _Float16* pd = h16 + (size_t)dst * CH + q * 16;
            const _Float16* ps = h16 + (size_t)src * CH + q * 16;
            half8 d0 = *(const half8*)(pd);
            half8 d1 = *(const half8*)(pd + 8);
            half8 s0 = *(const half8*)(ps);
            half8 s1 = *(const half8*)(ps + 8);
            *(half8*)(Zs + e * ZSTR + q * 16)          = d0;
            *(half8*)(Zs + e * ZSTR + q * 16 + 8)      = d1;
            *(half8*)(Zs + e * ZSTR + 64 + q * 16)     = s0;
            *(half8*)(Zs + e * ZSTR + 64 + q * 16 + 8) = s1;
            if (q == 0) {
                dstL[e] = dst;
                eaL[e] = ea[p];
            }
        }
        __syncthreads();   // B1: Z + metadata staged

        // ---- K-loop: 4 steps x (4 rt x 2) MFMA ----
        floatx4 accf[4], accs[4];
#pragma unroll
        for (int rt = 0; rt < 4; ++rt) {
#pragma unroll
            for (int r = 0; r < 4; ++r) {
                accf[rt][r] = biasf;
                accs[rt][r] = biass;
            }
        }
#pragma unroll
        for (int ks = 0; ks < 4; ++ks) {
#pragma unroll
            for (int rt = 0; rt < 4; ++rt) {
                half8 a = *(const half8*)(Zs + (rt * 16 + l15) * ZSTR + ks * 32 + quad * 8);
                accf[rt] = __builtin_amdgcn_mfma_f32_16x16x32_f16(a, wfr[ks], accf[rt], 0, 0, 0);
                accs[rt] = __builtin_amdgcn_mfma_f32_16x16x32_f16(a, wsr[ks], accs[rt], 0, 0, 0);
            }
        }

        // ---- epilogue: activation + in-register run merge + global atomics --
        // lane's rows (ascending): rt*16 + quad*4 + r ; dst sorted ascending
        float pend = 0.0f;
        int pdst = dstL[quad * 4];
#pragma unroll
        for (int rt = 0; rt < 4; ++rt) {
            const int row0 = rt * 16 + quad * 4;
            float4 ea4 = *(const float4*)(eaL + row0);
            int4 d4 = *(const int4*)(dstL + row0);
            float eav[4] = {ea4.x, ea4.y, ea4.z, ea4.w};
            int dd[4] = {d4.x, d4.y, d4.z, d4.w};
#pragma unroll
            for (int r = 0; r < 4; ++r) {
                float f = fmaf(eav[r], wf128v, accf[rt][r]);
                float s = fmaf(eav[r], ws128v, accs[rt][r]);
                float sig = __builtin_amdgcn_rcpf(1.0f + __expf(-f));
                float sp = fmaxf(s, 0.0f) + __logf(1.0f + __expf(-fabsf(s)));
                float m = sig * sp;
                if (dd[r] != pdst) {
                    atomicAdd(agg + (size_t)pdst * CH + col, pend);
                    pend = 0.0f;
                    pdst = dd[r];
                }
                pend += m;
            }
        }
        atomicAdd(agg + (size_t)pdst * CH + col, pend);
        __syncthreads();   // B2: LDS reads done before next tile restages
    }
}

// ---------------- global mean pool: segmented walkers over sorted batch -----
#define POOL_BLOCKS 256
__global__ __launch_bounds__(256)
void pool_kernel(const float* __restrict__ h,
                 const int* __restrict__ batch,
                 float* __restrict__ pooled,   // [G,64] pre-zeroed
                 float* __restrict__ counts) { // [G]   pre-zeroed
    const int c = threadIdx.x & 63;
    const int walker = blockIdx.x * 4 + (threadIdx.x >> 6);
    const int nwalk = POOL_BLOCKS * 4;
    const int chunk = (N_NODES + nwalk - 1) / nwalk;
    int r0 = walker * chunk;
    int r1 = min(N_NODES, r0 + chunk);
    if (r0 >= r1) return;

    int cur = batch[r0];
    float acc = 0.0f;
    int runlen = 0;
    for (int r = r0; r < r1; ++r) {
        int b = batch[r];
        if (b != cur) {
            atomicAdd(&pooled[cur * CH + c], acc);
            if (c == 0) atomicAdd(&counts[cur], (float)runlen);
            acc = 0.0f;
            runlen = 0;
            cur = b;
        }
        acc += h[(size_t)r * CH + c];
        ++runlen;
    }
    atomicAdd(&pooled[cur * CH + c], acc);
    if (c == 0) atomicAdd(&counts[cur], (float)runlen);
}

// ---------------- head ----------------
__global__ void head_kernel(const float* __restrict__ pooled,
                            const float* __restrict__ counts,
                            const float* __restrict__ W1,
                            const float* __restrict__ b1,
                            const float* __restrict__ W2,
                            const float* __restrict__ b2,
                            float* __restrict__ out) {
    int gph = blockIdx.x;
    int t = threadIdx.x;  // 64
    __shared__ float p[64];
    __shared__ float h1[32];
    float cnt = fmaxf(counts[gph], 1.0f);
    p[t] = pooled[gph * CH + t] / cnt;
    __syncthreads();
    if (t < 32) {
        float acc = b1[t];
#pragma unroll
        for (int c = 0; c < 64; ++c)
            acc = fmaf(p[c], W1[c * 32 + t], acc);
        h1[t] = fmaxf(acc, 0.0f);
    }
    __syncthreads();
    if (t == 0) {
        float acc = b2[0];
#pragma unroll
        for (int j = 0; j < 32; ++j)
            acc = fmaf(h1[j], W2[j], acc);
        out[gph] = acc;
    }
}

extern "C" void kernel_launch(void* const* d_in, const int* in_sizes, int n_in,
                              void* d_out, int out_size, void* d_ws, size_t ws_size,
                              hipStream_t stream) {
    const float* x     = (const float*)d_in[0];
    const int*   ei    = (const int*)d_in[1];
    const float* ea    = (const float*)d_in[2];
    const int*   batch = (const int*)d_in[3];
    const float* W_in  = (const float*)d_in[4];
    const float* b_in  = (const float*)d_in[5];
    const float* g0    = (const float*)d_in[6];
    const float* beta0 = (const float*)d_in[7];

    const float* Wf[3] = {(const float*)d_in[8],  (const float*)d_in[14], (const float*)d_in[20]};
    const float* bfv[3]= {(const float*)d_in[9],  (const float*)d_in[15], (const float*)d_in[21]};
    const float* Wsv[3]= {(const float*)d_in[10], (const float*)d_in[16], (const float*)d_in[22]};
    const float* bsv[3]= {(const float*)d_in[11], (const float*)d_in[17], (const float*)d_in[23]};
    const float* gm[3] = {(const float*)d_in[12], (const float*)d_in[18], (const float*)d_in[24]};
    const float* bb[3] = {(const float*)d_in[13], (const float*)d_in[19], (const float*)d_in[25]};

    const float* W1 = (const float*)d_in[26];
    const float* b1 = (const float*)d_in[27];
    const float* W2 = (const float*)d_in[28];
    const float* b2 = (const float*)d_in[29];

    float* out = (float*)d_out;

    // ---- workspace layout (byte-based) ----
    char* base = (char*)d_ws;
    size_t off = 0;
    float* hA = (float*)(base + off);        off += (size_t)NC * 4;
    float* hB = (float*)(base + off);        off += (size_t)NC * 4;
    _Float16* h16 = (_Float16*)(base + off); off += (size_t)NC * 2;
    _Float16* WT  = (_Float16*)(base + off); off += 3 * 128 * 128 * 2;
    float* w128   = (float*)(base + off);    off += 3 * 128 * 4;
    float* biasL  = (float*)(base + off);    off += 3 * 128 * 4;
    int* cursor   = (int*)(base + off);      off += (size_t)N_NODES * 4;
    int* sdst     = (int*)(base + off);      off += (size_t)N_EDGES * 4;
    int* perm     = (int*)(base + off);      off += (size_t)N_EDGES * 4;
    // ---- contiguous zero-region ----
    char* zbase   = base + off;
    int* rowptr   = (int*)(base + off);      off += (size_t)(N_NODES + 1) * 4;
    float* stats4 = (float*)(base + off);    off += 4 * 128 * 4;   // stats[l], l=0..3
    float* pooled = (float*)(base + off);    off += (size_t)N_GRAPHS * CH * 4;
    float* counts = (float*)(base + off);    off += (size_t)N_GRAPHS * 4;
    size_t zbytes = (size_t)(base + off - zbase);

    const int elemBlocks = (NC + 255) / 256;
    const int edgeBlocks = (N_EDGES + 255) / 256;

    // ---- one memset for all small zero-init buffers ----
    hipMemsetAsync(zbase, 0, zbytes, stream);

    // ---- sort edges by dst (perm + sdst) ----
    hist_kernel<<<edgeBlocks, 256, 0, stream>>>(ei, rowptr);
    scan_kernel<<<1, 1024, 0, stream>>>(rowptr, cursor);
    scatter_perm_kernel<<<edgeBlocks, 256, 0, stream>>>(ei, cursor, perm);
    fill_sdst_kernel<<<(N_NODES + 255) / 256, 256, 0, stream>>>(rowptr, sdst);

    // ---- prep f16 transposed weights ----
    for (int l = 0; l < 3; ++l)
        prep_weights_kernel<<<64, 256, 0, stream>>>(Wf[l], Wsv[l], bfv[l], bsv[l],
                                                    WT + l * 128 * 128, w128 + l * 128,
                                                    biasL + l * 128);

    // ---- input embedding + BN0 stats fused, then apply ----
    embed_stats_kernel<<<512, 256, 0, stream>>>(x, W_in, b_in, hA, stats4);
    bn_apply_kernel<true, false, true><<<elemBlocks, 256, 0, stream>>>(
        hA, nullptr, stats4, g0, beta0, h16);

    float* hcur = hA;
    float* hnext = hB;

    for (int l = 0; l < 3; ++l) {
        hipMemsetAsync(hnext, 0, (size_t)NC * sizeof(float), stream);
        edge_mfma_kernel<<<2048, 256, 0, stream>>>(h16, sdst, perm, ei, ea,
                                                   WT + l * 128 * 128, w128 + l * 128,
                                                   biasL + l * 128, hnext);
        float* statsL = stats4 + 128 * (l + 1);
        bn_stats_kernel<<<512, 256, 0, stream>>>(hnext, statsL);
        if (l < 2)
            bn_apply_kernel<true, true, true><<<elemBlocks, 256, 0, stream>>>(
                hnext, hcur, statsL, gm[l], bb[l], h16);
        else
            bn_apply_kernel<false, true, false><<<elemBlocks, 256, 0, stream>>>(
                hnext, hcur, statsL, gm[l], bb[l], nullptr);
        float* tmp = hcur; hcur = hnext; hnext = tmp;
    }

    // ---- pool + head ----
    pool_kernel<<<POOL_BLOCKS, 256, 0, stream>>>(hcur, batch, pooled, counts);
    head_kernel<<<N_GRAPHS, 64, 0, stream>>>(pooled, counts, W1, b1, W2, b2, out);
}

// Round 7
// 1158.985 us; speedup vs baseline: 1.1761x; 1.1761x over previous
//
#include <hip/hip_runtime.h>
#include <math.h>

#define N_NODES 100000
#define N_EDGES 1200000
#define N_GRAPHS 256
#define CH 64
#define NC (N_NODES * CH)
#define EPS 1e-5f

#define ZSTR 136   // f16 units per Z row (128 + pad) -> 4-bank rotation per row
#define ASTR 65    // f32 units per aggL row
#define NTILES (N_EDGES / 64)

typedef _Float16 half8 __attribute__((ext_vector_type(8)));
typedef float floatx4 __attribute__((ext_vector_type(4)));

// ---------------- embed + BN0 stats fused ----------------
__global__ void embed_stats_kernel(const float* __restrict__ x,
                                   const float* __restrict__ W,   // [12,64]
                                   const float* __restrict__ b,   // [64]
                                   float* __restrict__ out,       // [N,64]
                                   float* __restrict__ stats) {   // [128] pre-zeroed
    int c = threadIdx.x & 63;
    int sub = threadIdx.x >> 6;
    float s = 0.f, q = 0.f;
    for (int r = blockIdx.x * 4 + sub; r < N_NODES; r += gridDim.x * 4) {
        const float* xr = x + r * 12;
        float acc = b[c];
#pragma unroll
        for (int k = 0; k < 12; ++k)
            acc = fmaf(xr[k], W[k * CH + c], acc);
        out[(size_t)r * CH + c] = acc;
        s += acc;
        q = fmaf(acc, acc, q);
    }
    __shared__ float ls[4][64];
    __shared__ float lq[4][64];
    ls[sub][c] = s;
    lq[sub][c] = q;
    __syncthreads();
    if (sub == 0) {
        s = ls[0][c] + ls[1][c] + ls[2][c] + ls[3][c];
        q = lq[0][c] + lq[1][c] + lq[2][c] + lq[3][c];
        atomicAdd(&stats[c], s);
        atomicAdd(&stats[64 + c], q);
    }
}

// ---------------- BN stats ----------------
__global__ void bn_stats_kernel(const float* __restrict__ a,
                                float* __restrict__ stats) { // [128] pre-zeroed
    int c = threadIdx.x & 63;
    int sub = threadIdx.x >> 6;
    float s = 0.f, q = 0.f;
    for (int r = blockIdx.x * 4 + sub; r < N_NODES; r += gridDim.x * 4) {
        float v = a[(size_t)r * CH + c];
        s += v;
        q = fmaf(v, v, q);
    }
    __shared__ float ls[4][64];
    __shared__ float lq[4][64];
    ls[sub][c] = s;
    lq[sub][c] = q;
    __syncthreads();
    if (sub == 0) {
        s = ls[0][c] + ls[1][c] + ls[2][c] + ls[3][c];
        q = lq[0][c] + lq[1][c] + lq[2][c] + lq[3][c];
        atomicAdd(&stats[c], s);
        atomicAdd(&stats[64 + c], q);
    }
}

// ------- BN apply with fused finalize (+residual, +relu, +f16 copy) -------
template <bool RELU, bool RES, bool F16OUT>
__global__ void bn_apply_kernel(float* __restrict__ a,
                                const float* __restrict__ res,
                                const float* __restrict__ stats,
                                const float* __restrict__ gamma,
                                const float* __restrict__ beta,
                                _Float16* __restrict__ h16) {
    __shared__ float ab[128];
    if (threadIdx.x < 64) {
        int cc = threadIdx.x;
        float mean = stats[cc] * (1.0f / (float)N_NODES);
        float var  = stats[64 + cc] * (1.0f / (float)N_NODES) - mean * mean;
        float inv  = rsqrtf(var + EPS);
        float A = gamma[cc] * inv;
        ab[cc] = A;
        ab[64 + cc] = beta[cc] - mean * A;
    }
    __syncthreads();
    int idx = blockIdx.x * blockDim.x + threadIdx.x;
    if (idx >= NC) return;
    int c = idx & 63;
    float v = fmaf(a[idx], ab[c], ab[64 + c]);
    if (RES) v += res[idx];
    if (RELU) v = fmaxf(v, 0.f);
    a[idx] = v;
    if (F16OUT) h16[idx] = (_Float16)v;
}

// ---------------- counting sort of edges by dst ----------------
__global__ void hist_kernel(const int* __restrict__ ei,
                            int* __restrict__ rowptr) { // [N+1] pre-zeroed
    int e = blockIdx.x * blockDim.x + threadIdx.x;
    if (e < N_EDGES) atomicAdd(&rowptr[ei[N_EDGES + e] + 1], 1);
}

__global__ void scan_kernel(int* __restrict__ a, int* __restrict__ cursor) {
    __shared__ int wsum[16];
    __shared__ int carryS;
    int t = threadIdx.x;           // 1024 threads = 16 waves
    int lane = t & 63, w = t >> 6;
    if (t == 0) carryS = 0;
    __syncthreads();
    for (int base = 0; base <= N_NODES; base += 1024) {
        int i = base + t;
        int v = (i <= N_NODES) ? a[i] : 0;
        int s = v;
#pragma unroll
        for (int d = 1; d < 64; d <<= 1) {
            int o = __shfl_up(s, d);
            if (lane >= d) s += o;
        }
        if (lane == 63) wsum[w] = s;
        __syncthreads();
        if (w == 0) {
            int ws2 = (lane < 16) ? wsum[lane] : 0;
#pragma unroll
            for (int d = 1; d < 16; d <<= 1) {
                int o = __shfl_up(ws2, d);
                if (lane >= d) ws2 += o;
            }
            if (lane < 16) wsum[lane] = ws2;
        }
        __syncthreads();
        int waveoff = (w > 0) ? wsum[w - 1] : 0;
        int total = wsum[15];
        int res = s + waveoff + carryS;
        if (i <= N_NODES) {
            a[i] = res;
            if (i < N_NODES) cursor[i] = res;
        }
        __syncthreads();
        if (t == 0) carryS += total;
        __syncthreads();
    }
}

// one 8B random write per edge: sef[pos] = {src, ea_bits}
__global__ void scatter_kernel(const int* __restrict__ ei,
                               const float* __restrict__ ea,
                               int* __restrict__ cursor,
                               int2* __restrict__ sef) {
    int e = blockIdx.x * blockDim.x + threadIdx.x;
    if (e >= N_EDGES) return;
    int d = ei[N_EDGES + e];
    int pos = atomicAdd(&cursor[d], 1);
    sef[pos] = make_int2(ei[e], __float_as_int(ea[e]));
}

// sdst[pos] = d for pos in [rowptr[d], rowptr[d+1])  (sequential-ish writes)
__global__ void fill_sdst_kernel(const int* __restrict__ rowptr,
                                 int* __restrict__ sdst) {
    int d = blockIdx.x * blockDim.x + threadIdx.x;
    if (d >= N_NODES) return;
    int s = rowptr[d], e = rowptr[d + 1];
    for (int pos = s; pos < e; ++pos) sdst[pos] = d;
}

// ---------------- weight prep: WT[n][k] = W[k][n] in f16 ----------------
__global__ void prep_weights_kernel(const float* __restrict__ Wf,  // [129,64]
                                    const float* __restrict__ Ws,  // [129,64]
                                    const float* __restrict__ bf,
                                    const float* __restrict__ bs,
                                    _Float16* __restrict__ WT,     // [128,128]
                                    float* __restrict__ w128,      // [128]
                                    float* __restrict__ bias) {    // [128]
    int idx = blockIdx.x * blockDim.x + threadIdx.x;  // 16384
    if (idx < 128 * 128) {
        int n = idx >> 7;
        int k = idx & 127;
        float v = (n < 64) ? Wf[k * 64 + n] : Ws[k * 64 + (n - 64)];
        WT[idx] = (_Float16)v;
    }
    if (idx < 128) {
        w128[idx] = (idx < 64) ? Wf[128 * 64 + idx] : Ws[128 * 64 + (idx - 64)];
        bias[idx] = (idx < 64) ? bf[idx] : bs[idx - 64];
    }
}

// ---------------- CGConv edge kernel: f16 MFMA + LDS agg + split flush ------
// 256 threads = 4 waves; wave w owns output cols [w*16,+16) for f AND s.
// LDS aggregation (aggL) keeps scatter off HBM; flush uses plain stores for
// tile-interior dsts (complete sums, full 256B rows) and atomicAdd only for
// the 2 boundary dsts per tile.
__global__ __launch_bounds__(256, 4)
void edge_mfma_kernel(const _Float16* __restrict__ h16, // [N,64] f16
                      const int* __restrict__ sdst,     // [E] sorted dst
                      const int2* __restrict__ sef,     // [E] {src, ea}
                      const _Float16* __restrict__ WT,  // [128,128]
                      const float* __restrict__ w128,   // [128]
                      const float* __restrict__ bias,   // [128]
                      float* __restrict__ agg) {        // [N,64] pre-zeroed
    __shared__ __align__(16) _Float16 Zs[64 * ZSTR];
    __shared__ __align__(16) float aggL[64 * ASTR];
    __shared__ __align__(16) int dstL[64];
    __shared__ __align__(16) int lidxL[64];
    __shared__ __align__(16) int dstlist[64];
    __shared__ __align__(16) float eaL[64];
    __shared__ int ndistS;

    const int t = threadIdx.x;
    const int lane = t & 63;
    const int w = t >> 6;          // wave 0..3
    const int l15 = lane & 15;
    const int quad = lane >> 4;    // 0..3
    const int col = w * 16 + l15;  // this lane's output column (f and s)

    half8 wfr[4], wsr[4];
#pragma unroll
    for (int ks = 0; ks < 4; ++ks) {
        wfr[ks] = *(const half8*)(WT + col * 128 + ks * 32 + quad * 8);
        wsr[ks] = *(const half8*)(WT + (64 + col) * 128 + ks * 32 + quad * 8);
    }
    const float biasf = bias[col];
    const float biass = bias[64 + col];
    const float wf128v = w128[col];
    const float ws128v = w128[64 + col];

    for (int tile = blockIdx.x; tile < NTILES; tile += gridDim.x) {
        const int base = tile * 64;

        // ---- stage Z (f16 gather) ----
        {
            const int e = t >> 2, q = t & 3;
            const int dst = sdst[base + e];
            const int src = sef[base + e].x;
            const _Float16* pd = h16 + (size_t)dst * CH + q * 16;
            const _Float16* ps = h16 + (size_t)src * CH + q * 16;
            half8 d0 = *(const half8*)(pd);
            half8 d1 = *(const half8*)(pd + 8);
            half8 s0 = *(const half8*)(ps);
            half8 s1 = *(const half8*)(ps + 8);
            *(half8*)(Zs + e * ZSTR + q * 16)          = d0;
            *(half8*)(Zs + e * ZSTR + q * 16 + 8)      = d1;
            *(half8*)(Zs + e * ZSTR + 64 + q * 16)     = s0;
            *(half8*)(Zs + e * ZSTR + 64 + q * 16 + 8) = s1;
        }
        // ---- wave 0: dst metadata + local-dst-id run scan ----
        if (w == 0) {
            int d = sdst[base + lane];
            int2 sf = sef[base + lane];
            dstL[lane] = d;
            eaL[lane] = __int_as_float(sf.y);
            int dprev = __shfl_up(d, 1);
            int flag = (lane > 0 && d != dprev) ? 1 : 0;
            int s = flag;
#pragma unroll
            for (int dd = 1; dd < 64; dd <<= 1) {
                int o = __shfl_up(s, dd);
                if (lane >= dd) s += o;
            }
            lidxL[lane] = s;
            if (lane == 0 || flag) dstlist[s] = d;
            if (lane == 63) ndistS = s + 1;
        }
        // ---- zero aggL ----
        {
            float4 z4 = {0.f, 0.f, 0.f, 0.f};
            for (int i = t * 4; i < 64 * ASTR; i += 1024)
                *(float4*)(aggL + i) = z4;
        }
        __syncthreads();   // B1

        // ---- K-loop: 4 steps x (4 rt x 2) MFMA ----
        floatx4 accf[4], accs[4];
#pragma unroll
        for (int rt = 0; rt < 4; ++rt) {
#pragma unroll
            for (int r = 0; r < 4; ++r) {
                accf[rt][r] = biasf;
                accs[rt][r] = biass;
            }
        }
#pragma unroll
        for (int ks = 0; ks < 4; ++ks) {
#pragma unroll
            for (int rt = 0; rt < 4; ++rt) {
                half8 a = *(const half8*)(Zs + (rt * 16 + l15) * ZSTR + ks * 32 + quad * 8);
                accf[rt] = __builtin_amdgcn_mfma_f32_16x16x32_f16(a, wfr[ks], accf[rt], 0, 0, 0);
                accs[rt] = __builtin_amdgcn_mfma_f32_16x16x32_f16(a, wsr[ks], accs[rt], 0, 0, 0);
            }
        }

        // ---- epilogue: activation + run-merged LDS atomics ----
#pragma unroll
        for (int rt = 0; rt < 4; ++rt) {
            const int row0 = rt * 16 + quad * 4;
            float4 ea4 = *(const float4*)(eaL + row0);
            int4 li4 = *(const int4*)(lidxL + row0);
            float eav[4] = {ea4.x, ea4.y, ea4.z, ea4.w};
            int lidx[4] = {li4.x, li4.y, li4.z, li4.w};
            float pend = 0.0f;
            int plidx = lidx[0];
#pragma unroll
            for (int r = 0; r < 4; ++r) {
                float f = fmaf(eav[r], wf128v, accf[rt][r]);
                float s = fmaf(eav[r], ws128v, accs[rt][r]);
                float sig = __builtin_amdgcn_rcpf(1.0f + __expf(-f));
                float sp = fmaxf(s, 0.0f) + __logf(1.0f + __expf(-fabsf(s)));
                float m = sig * sp;
                if (lidx[r] != plidx) {
                    atomicAdd(aggL + plidx * ASTR + col, pend);
                    pend = 0.0f;
                    plidx = lidx[r];
                }
                pend += m;
            }
            atomicAdd(aggL + plidx * ASTR + col, pend);
        }
        __syncthreads();   // B2

        // ---- flush: plain stores for interior dsts, atomics for boundary ----
        {
            int nd = ndistS;
            for (int i = t; i < nd * 64; i += 256) {
                int rr = i >> 6, cc = i & 63;
                float v = aggL[rr * ASTR + cc];
                size_t gi = (size_t)dstlist[rr] * CH + cc;
                if (rr == 0 || rr == nd - 1) atomicAdd(agg + gi, v);
                else agg[gi] = v;
            }
        }
        __syncthreads();   // B3
    }
}

// ---------------- global mean pool: segmented walkers over sorted batch -----
#define POOL_BLOCKS 256
__global__ __launch_bounds__(256)
void pool_kernel(const float* __restrict__ h,
                 const int* __restrict__ batch,
                 float* __restrict__ pooled,   // [G,64] pre-zeroed
                 float* __restrict__ counts) { // [G]   pre-zeroed
    const int c = threadIdx.x & 63;
    const int walker = blockIdx.x * 4 + (threadIdx.x >> 6);
    const int nwalk = POOL_BLOCKS * 4;
    const int chunk = (N_NODES + nwalk - 1) / nwalk;
    int r0 = walker * chunk;
    int r1 = min(N_NODES, r0 + chunk);
    if (r0 >= r1) return;

    int cur = batch[r0];
    float acc = 0.0f;
    int runlen = 0;
    for (int r = r0; r < r1; ++r) {
        int b = batch[r];
        if (b != cur) {
            atomicAdd(&pooled[cur * CH + c], acc);
            if (c == 0) atomicAdd(&counts[cur], (float)runlen);
            acc = 0.0f;
            runlen = 0;
            cur = b;
        }
        acc += h[(size_t)r * CH + c];
        ++runlen;
    }
    atomicAdd(&pooled[cur * CH + c], acc);
    if (c == 0) atomicAdd(&counts[cur], (float)runlen);
}

// ---------------- head ----------------
__global__ void head_kernel(const float* __restrict__ pooled,
                            const float* __restrict__ counts,
                            const float* __restrict__ W1,
                            const float* __restrict__ b1,
                            const float* __restrict__ W2,
                            const float* __restrict__ b2,
                            float* __restrict__ out) {
    int gph = blockIdx.x;
    int t = threadIdx.x;  // 64
    __shared__ float p[64];
    __shared__ float h1[32];
    float cnt = fmaxf(counts[gph], 1.0f);
    p[t] = pooled[gph * CH + t] / cnt;
    __syncthreads();
    if (t < 32) {
        float acc = b1[t];
#pragma unroll
        for (int c = 0; c < 64; ++c)
            acc = fmaf(p[c], W1[c * 32 + t], acc);
        h1[t] = fmaxf(acc, 0.0f);
    }
    __syncthreads();
    if (t == 0) {
        float acc = b2[0];
#pragma unroll
        for (int j = 0; j < 32; ++j)
            acc = fmaf(h1[j], W2[j], acc);
        out[gph] = acc;
    }
}

extern "C" void kernel_launch(void* const* d_in, const int* in_sizes, int n_in,
                              void* d_out, int out_size, void* d_ws, size_t ws_size,
                              hipStream_t stream) {
    const float* x     = (const float*)d_in[0];
    const int*   ei    = (const int*)d_in[1];
    const float* ea    = (const float*)d_in[2];
    const int*   batch = (const int*)d_in[3];
    const float* W_in  = (const float*)d_in[4];
    const float* b_in  = (const float*)d_in[5];
    const float* g0    = (const float*)d_in[6];
    const float* beta0 = (const float*)d_in[7];

    const float* Wf[3] = {(const float*)d_in[8],  (const float*)d_in[14], (const float*)d_in[20]};
    const float* bfv[3]= {(const float*)d_in[9],  (const float*)d_in[15], (const float*)d_in[21]};
    const float* Wsv[3]= {(const float*)d_in[10], (const float*)d_in[16], (const float*)d_in[22]};
    const float* bsv[3]= {(const float*)d_in[11], (const float*)d_in[17], (const float*)d_in[23]};
    const float* gm[3] = {(const float*)d_in[12], (const float*)d_in[18], (const float*)d_in[24]};
    const float* bb[3] = {(const float*)d_in[13], (const float*)d_in[19], (const float*)d_in[25]};

    const float* W1 = (const float*)d_in[26];
    const float* b1 = (const float*)d_in[27];
    const float* W2 = (const float*)d_in[28];
    const float* b2 = (const float*)d_in[29];

    float* out = (float*)d_out;

    // ---- workspace layout (byte-based) ----
    char* base = (char*)d_ws;
    size_t off = 0;
    float* hA = (float*)(base + off);        off += (size_t)NC * 4;
    float* hB = (float*)(base + off);        off += (size_t)NC * 4;
    _Float16* h16 = (_Float16*)(base + off); off += (size_t)NC * 2;
    _Float16* WT  = (_Float16*)(base + off); off += 3 * 128 * 128 * 2;
    float* w128   = (float*)(base + off);    off += 3 * 128 * 4;
    float* biasL  = (float*)(base + off);    off += 3 * 128 * 4;
    int* cursor   = (int*)(base + off);      off += (size_t)N_NODES * 4;
    int* sdst     = (int*)(base + off);      off += (size_t)N_EDGES * 4;
    int2* sef     = (int2*)(base + off);     off += (size_t)N_EDGES * 8;
    // ---- contiguous zero-region ----
    char* zbase   = base + off;
    int* rowptr   = (int*)(base + off);      off += (size_t)(N_NODES + 1) * 4;
    float* stats4 = (float*)(base + off);    off += 4 * 128 * 4;   // stats[l], l=0..3
    float* pooled = (float*)(base + off);    off += (size_t)N_GRAPHS * CH * 4;
    float* counts = (float*)(base + off);    off += (size_t)N_GRAPHS * 4;
    size_t zbytes = (size_t)(base + off - zbase);

    const int elemBlocks = (NC + 255) / 256;
    const int edgeBlocks = (N_EDGES + 255) / 256;

    hipMemsetAsync(zbase, 0, zbytes, stream);

    // ---- sort edges by dst (sdst + packed {src,ea}) ----
    hist_kernel<<<edgeBlocks, 256, 0, stream>>>(ei, rowptr);
    scan_kernel<<<1, 1024, 0, stream>>>(rowptr, cursor);
    scatter_kernel<<<edgeBlocks, 256, 0, stream>>>(ei, ea, cursor, sef);
    fill_sdst_kernel<<<(N_NODES + 255) / 256, 256, 0, stream>>>(rowptr, sdst);

    // ---- prep f16 transposed weights ----
    for (int l = 0; l < 3; ++l)
        prep_weights_kernel<<<64, 256, 0, stream>>>(Wf[l], Wsv[l], bfv[l], bsv[l],
                                                    WT + l * 128 * 128, w128 + l * 128,
                                                    biasL + l * 128);

    // ---- input embedding + BN0 stats fused, then apply ----
    embed_stats_kernel<<<512, 256, 0, stream>>>(x, W_in, b_in, hA, stats4);
    bn_apply_kernel<true, false, true><<<elemBlocks, 256, 0, stream>>>(
        hA, nullptr, stats4, g0, beta0, h16);

    float* hcur = hA;
    float* hnext = hB;

    for (int l = 0; l < 3; ++l) {
        hipMemsetAsync(hnext, 0, (size_t)NC * sizeof(float), stream);
        edge_mfma_kernel<<<1024, 256, 0, stream>>>(h16, sdst, sef,
                                                   WT + l * 128 * 128, w128 + l * 128,
                                                   biasL + l * 128, hnext);
        float* statsL = stats4 + 128 * (l + 1);
        bn_stats_kernel<<<512, 256, 0, stream>>>(hnext, statsL);
        if (l < 2)
            bn_apply_kernel<true, true, true><<<elemBlocks, 256, 0, stream>>>(
                hnext, hcur, statsL, gm[l], bb[l], h16);
        else
            bn_apply_kernel<false, true, false><<<elemBlocks, 256, 0, stream>>>(
                hnext, hcur, statsL, gm[l], bb[l], nullptr);
        float* tmp = hcur; hcur = hnext; hnext = tmp;
    }

    // ---- pool + head ----
    pool_kernel<<<POOL_BLOCKS, 256, 0, stream>>>(hcur, batch, pooled, counts);
    head_kernel<<<N_GRAPHS, 64, 0, stream>>>(pooled, counts, W1, b1, W2, b2, out);
}